// Round 4
// baseline (94.979 us; speedup 1.0000x reference)
//
#include <hip/hip_runtime.h>

typedef unsigned short u16;
typedef __attribute__((ext_vector_type(8))) short s16x8;
typedef __attribute__((ext_vector_type(4))) float f32x4;

#define MFMA16(a, b, c) __builtin_amdgcn_mfma_f32_16x16x32_bf16((a), (b), (c), 0, 0, 0)

// round-to-nearest-even f32 -> bf16 (raw u16)
__device__ __forceinline__ u16 f2bf(float f) {
  unsigned u = __float_as_uint(f);
  u += 0x7fffu + ((u >> 16) & 1u);
  return (u16)(u >> 16);
}

// async global->LDS, 16B per lane, wave-uniform LDS base (+lane*16 by HW)
__device__ __forceinline__ void gld_lds16(const void* g, void* l) {
  __builtin_amdgcn_global_load_lds(
      (const __attribute__((address_space(1))) void*)g,
      (__attribute__((address_space(3))) void*)l, 16, 0, 0);
}

// ---------------------------------------------------------------------------
// cast X f32 -> bf16, same [8192][512] layout, 8 elems/thread
// ---------------------------------------------------------------------------
__global__ __launch_bounds__(256) void xcast(const float* __restrict__ X,
                                             u16* __restrict__ Xb) {
  size_t idx = (size_t)blockIdx.x * 256 + threadIdx.x;
  const float4 f0 = *(const float4*)(X + idx * 8);
  const float4 f1 = *(const float4*)(X + idx * 8 + 4);
  float fs[8] = {f0.x, f0.y, f0.z, f0.w, f1.x, f1.y, f1.z, f1.w};
  s16x8 hv;
#pragma unroll
  for (int j = 0; j < 8; ++j) hv[j] = (short)f2bf(fs[j]);
  *(s16x8*)(Xb + idx * 8) = hv;
}

// ---------------------------------------------------------------------------
// transpose + cast weights: W[K][N] f32 -> T[N][K] bf16.
// PERM=1 (wqkv): T row n' = source col h*192 + t*64 + d  (q/k/v grouped)
// ---------------------------------------------------------------------------
template <int PERM>
__global__ __launch_bounds__(256) void wcastT(const float* __restrict__ W, int K, int N,
                                              u16* __restrict__ T) {
  int idx = blockIdx.x * 256 + threadIdx.x;
  int total = N * (K >> 3);
  if (idx >= total) return;
  int n = idx % N;
  int kc = idx / N;
  int src_c;
  if (PERM) {
    int t = n >> 9, ct = n & 511, h = ct >> 6, d = ct & 63;
    src_c = h * 192 + t * 64 + d;
  } else {
    src_c = n;
  }
  s16x8 hv;
#pragma unroll
  for (int i = 0; i < 8; ++i) hv[i] = (short)f2bf(W[(size_t)(kc * 8 + i) * N + src_c]);
  *(s16x8*)(T + (size_t)n * K + (size_t)kc * 8) = hv;
}

// ---------------------------------------------------------------------------
// 128x128 bf16 GEMM, BK=64, single-buffered 32KB LDS (m97 structure),
// global_load_lds w=16 with 8-slot XOR involution (2-way = free).
// A[M][512], B[N][512] row-major bf16 (K contiguous).
// EPI=1 (gemm1): by 0-3 -> q (scaled by QS), 4-7 -> k, 8-11 -> v via LDS
//   transpose to vT[bh][64][2048] (coalesced 16B stores).
// EPI=0 (gemm2): f32 OUT.
// ---------------------------------------------------------------------------
template <int EPI>
__global__ __launch_bounds__(256) void gemm_bf16(
    const u16* __restrict__ A, const u16* __restrict__ B,
    float* __restrict__ OUT,
    u16* __restrict__ qo, u16* __restrict__ ko, u16* __restrict__ vto) {
  __shared__ u16 LDS[EPI ? 16640 : 16384];
  u16* SA = LDS;
  u16* SB = LDS + 8192;
  const int tid = threadIdx.x;
  const int w = tid >> 6, lane = tid & 63;
  const int l15 = lane & 15, l4 = lane >> 4;
  const int row0 = blockIdx.x * 128;
  const int col0 = blockIdx.y * 128;
  const int wr = w >> 1, wc = w & 1;

  const int lrow = lane >> 3, lslot = lane & 7;
  const int srcoff = lrow * 1024 + ((lslot ^ lrow) << 4);  // bytes
  const char* pA = (const char*)A + (size_t)(row0 + w * 32) * 1024 + srcoff;
  const char* pB = (const char*)B + (size_t)(col0 + w * 32) * 1024 + srcoff;
  u16* sAw = SA + (w * 32) * 64;
  u16* sBw = SB + (w * 32) * 64;

  const f32x4 fz = {0.f, 0.f, 0.f, 0.f};
  f32x4 acc[4][4];
  for (int a = 0; a < 4; ++a)
    for (int b = 0; b < 4; ++b) acc[a][b] = fz;

  for (int t = 0; t < 8; ++t) {
    const size_t kb = (size_t)t * 128;
#pragma unroll
    for (int j = 0; j < 4; ++j) {
      gld_lds16(pA + j * 8192 + kb, sAw + j * 512);
      gld_lds16(pB + j * 8192 + kb, sBw + j * 512);
    }
    __syncthreads();
#pragma unroll
    for (int ks = 0; ks < 2; ++ks) {
      s16x8 af[4], bf[4];
#pragma unroll
      for (int mi = 0; mi < 4; ++mi) {
        const int r = wr * 64 + mi * 16 + l15;
        const int sl = (ks * 4 + l4) ^ (r & 7);
        af[mi] = *(const s16x8*)&SA[r * 64 + sl * 8];
      }
#pragma unroll
      for (int nj = 0; nj < 4; ++nj) {
        const int r = wc * 64 + nj * 16 + l15;
        const int sl = (ks * 4 + l4) ^ (r & 7);
        bf[nj] = *(const s16x8*)&SB[r * 64 + sl * 8];
      }
#pragma unroll
      for (int nj = 0; nj < 4; ++nj)
#pragma unroll
        for (int mi = 0; mi < 4; ++mi) acc[mi][nj] = MFMA16(af[mi], bf[nj], acc[mi][nj]);
    }
    __syncthreads();
  }

  if (EPI == 0) {
#pragma unroll
    for (int mi = 0; mi < 4; ++mi)
#pragma unroll
      for (int nj = 0; nj < 4; ++nj)
#pragma unroll
        for (int rg = 0; rg < 4; ++rg) {
          int r_g = row0 + wr * 64 + mi * 16 + l4 * 4 + rg;
          int c_g = col0 + wc * 64 + nj * 16 + l15;
          OUT[(size_t)r_g * 512 + c_g] = acc[mi][nj][rg];
        }
    return;
  }

  // ---- gemm1 epilogue ----
  const int by = blockIdx.y;
  const int b = row0 >> 11, srow = row0 & 2047;
  if (by < 8) {
    const int isq = (by < 4);
    const float QS = 0.06375874f;  // 512^-0.5 * log2(e)
    u16* dst = isq ? qo : ko;
#pragma unroll
    for (int mi = 0; mi < 4; ++mi)
#pragma unroll
      for (int nj = 0; nj < 4; ++nj)
#pragma unroll
        for (int rg = 0; rg < 4; ++rg) {
          float v = acc[mi][nj][rg];
          if (isq) v *= QS;
          int s = srow + wr * 64 + mi * 16 + l4 * 4 + rg;
          int ct = ((by & 3) * 128 + wc * 64 + nj * 16 + l15);
          int h = ct >> 6, d = ct & 63;
          dst[(((size_t)b * 8 + h) * 2048 + s) * 64 + d] = f2bf(v);
        }
  } else {
    // v: transpose via LDS (pitch 130) -> vT[bh][64][2048]
#pragma unroll
    for (int mi = 0; mi < 4; ++mi)
#pragma unroll
      for (int nj = 0; nj < 4; ++nj)
#pragma unroll
        for (int rg = 0; rg < 4; ++rg) {
          int c = wc * 64 + nj * 16 + l15;
          int s = wr * 64 + mi * 16 + l4 * 4 + rg;
          LDS[c * 130 + s] = f2bf(acc[mi][nj][rg]);
        }
    __syncthreads();
    const unsigned* LDSw = (const unsigned*)LDS;
    int c = tid >> 1, sh = tid & 1;
    int ct = (by - 8) * 128 + c;
    int h = ct >> 6, d = ct & 63;
    size_t o = (((size_t)b * 8 + h) * 64 + d) * 2048 + srow + sh * 64;
    unsigned wbuf[32];
#pragma unroll
    for (int p = 0; p < 32; ++p) wbuf[p] = LDSw[c * 65 + sh * 32 + p];
#pragma unroll
    for (int j = 0; j < 8; ++j) {
      uint4 u = {wbuf[j * 4], wbuf[j * 4 + 1], wbuf[j * 4 + 2], wbuf[j * 4 + 3]};
      *(uint4*)(vto + o + j * 8) = u;
    }
  }
}

// ---------------------------------------------------------------------------
// Banded flash attention, no-max softmax (scores provably < ~2^4):
//   p = exp2(S_log2), masked p = 0, l accumulated per-lane, reduced once.
// Block = (b, h, qtile of 64). 4 waves x 16 q-rows. Grid 1024 -> 50% occ.
// ---------------------------------------------------------------------------
__global__ __launch_bounds__(256) void attn_kernel(
    const u16* __restrict__ q, const u16* __restrict__ k,
    const u16* __restrict__ vt, u16* __restrict__ ao) {
  __shared__ u16 Ph[4][16][64];
  const int tid = threadIdx.x;
  const int w = tid >> 6, lane = tid & 63;
  const int l15 = lane & 15, l4 = lane >> 4;
  const int bid = blockIdx.x;
  const int qt = bid & 31, hh = (bid >> 5) & 7, b = bid >> 8;
  const size_t base = (size_t)(b * 8 + hh) * 2048 * 64;
  const int q0 = qt * 64 + w * 16;  // this wave's 16 rows

  // Q A-frags: lane holds Q[row=l15][k = ks*32 + l4*8 + j]
  s16x8 qf[2];
#pragma unroll
  for (int ks = 0; ks < 2; ++ks)
    qf[ks] = *(const s16x8*)(q + base + (size_t)(q0 + l15) * 64 + ks * 32 + l4 * 8);

  const f32x4 fz = {0.f, 0.f, 0.f, 0.f};
  f32x4 O[4];
  for (int nd = 0; nd < 4; ++nd) O[nd] = fz;
  float l_acc[4] = {0.f, 0.f, 0.f, 0.f};

  const int c0 = (q0 - 128) < 0 ? 0 : ((q0 - 128) >> 6);
  const int c1 = ((q0 + 15 + 128) >> 6) > 31 ? 31 : ((q0 + 15 + 128) >> 6);
  for (int c = c0; c <= c1; ++c) {
    const int kb = c * 64;
    // S = Q K^T
    f32x4 S[4];
    for (int nj = 0; nj < 4; ++nj) S[nj] = fz;
#pragma unroll
    for (int nj = 0; nj < 4; ++nj)
#pragma unroll
      for (int ks = 0; ks < 2; ++ks) {
        s16x8 kf = *(const s16x8*)(k + base + (size_t)(kb + nj * 16 + l15) * 64 + ks * 32 + l4 * 8);
        S[nj] = MFMA16(qf[ks], kf, S[nj]);
      }
    // p = exp2(S); mask -> 0; stash bf16 in swizzled per-wave LDS
    const bool needmask = (kb + 63 - q0 > 128) || (q0 + 15 - kb > 128);
#pragma unroll
    for (int nj = 0; nj < 4; ++nj)
#pragma unroll
      for (int rg = 0; rg < 4; ++rg) {
        const int row = l4 * 4 + rg;          // 0..15
        const int col = nj * 16 + l15;        // 0..63
        float p = exp2f(S[nj][rg]);
        if (needmask) {
          int dd = (kb + col) - (q0 + row);
          if (dd > 128 || dd < -128) p = 0.f;
        }
        l_acc[rg] += p;
        const int e = (((col >> 3) ^ (row & 7)) << 3) + (col & 7);
        Ph[w][row][e] = f2bf(p);
      }
    // O += P V
#pragma unroll
    for (int ksp = 0; ksp < 2; ++ksp) {
      const int prow = l15;
      const int sl = (ksp * 4 + l4) ^ (prow & 7);
      s16x8 pa = *(const s16x8*)&Ph[w][prow][sl * 8];
#pragma unroll
      for (int nd = 0; nd < 4; ++nd) {
        s16x8 vf = *(const s16x8*)(vt + base + (size_t)(nd * 16 + l15) * 2048 + kb + ksp * 32 + l4 * 8);
        O[nd] = MFMA16(pa, vf, O[nd]);
      }
    }
  }
  // epilogue: row-sum reduce l (over the 16-lane col groups), normalize, store
#pragma unroll
  for (int rg = 0; rg < 4; ++rg) {
    float s = l_acc[rg];
    s += __shfl_xor(s, 1);
    s += __shfl_xor(s, 2);
    s += __shfl_xor(s, 4);
    s += __shfl_xor(s, 8);
    l_acc[rg] = 1.0f / s;
  }
#pragma unroll
  for (int rg = 0; rg < 4; ++rg) {
    const int s_g = q0 + l4 * 4 + rg;
#pragma unroll
    for (int nd = 0; nd < 4; ++nd) {
      float v = O[nd][rg] * l_acc[rg];
      const int c_g = hh * 64 + nd * 16 + l15;
      ao[((size_t)b * 2048 + s_g) * 512 + c_g] = f2bf(v);
    }
  }
}

// ---------------------------------------------------------------------------
extern "C" void kernel_launch(void* const* d_in, const int* in_sizes, int n_in,
                              void* d_out, int out_size, void* d_ws, size_t ws_size,
                              hipStream_t stream) {
  const float* x = (const float*)d_in[0];      // [4,2048,512]
  const float* wqkv = (const float*)d_in[1];   // [512,1536]
  const float* wproj = (const float*)d_in[2];  // [512,512]
  float* out = (float*)d_out;                  // [4,2048,512]

  char* ws = (char*)d_ws;
  size_t off = 0;
  auto alloc = [&](size_t bytes) {
    void* p = ws + off;
    off += (bytes + 255) & ~(size_t)255;
    return p;
  };
  const size_t E = (size_t)4 * 8 * 2048 * 64;
  u16* Xb  = (u16*)alloc(E * 2);
  u16* qb  = (u16*)alloc(E * 2);
  u16* kb  = (u16*)alloc(E * 2);
  u16* vtb = (u16*)alloc(E * 2);
  u16* aob = (u16*)alloc(E * 2);
  u16* wqT = (u16*)alloc((size_t)1536 * 512 * 2);
  u16* wpT = (u16*)alloc((size_t)512 * 512 * 2);

  xcast<<<dim3(2048), dim3(256), 0, stream>>>(x, Xb);
  wcastT<1><<<dim3(384), dim3(256), 0, stream>>>(wqkv, 512, 1536, wqT);
  wcastT<0><<<dim3(128), dim3(256), 0, stream>>>(wproj, 512, 512, wpT);
  gemm_bf16<1><<<dim3(64, 12), dim3(256), 0, stream>>>(Xb, wqT, nullptr, qb, kb, vtb);
  attn_kernel<<<dim3(1024), dim3(256), 0, stream>>>(qb, kb, vtb, aob);
  gemm_bf16<0><<<dim3(64, 4), dim3(256), 0, stream>>>(aob, wpT, out, nullptr, nullptr, nullptr);
}